// Round 11
// baseline (327.256 us; speedup 1.0000x reference)
//
#include <hip/hip_runtime.h>
#include <stdint.h>

#define NF 8192
#define NX 2048
#define MROWS 8192
#define NGROUPS 32
#define NT 32   // NX/64 K-tiles

typedef unsigned short u16;
typedef __bf16 bf16x8 __attribute__((ext_vector_type(8)));
typedef float f32x4 __attribute__((ext_vector_type(4)));

#define AS1 __attribute__((address_space(1)))
#define AS3 __attribute__((address_space(3)))

// async global->LDS, 16B/lane; LDS dest = wave-uniform base + lane*16.
__device__ __forceinline__ void glds16(const void* g, void* l) {
    __builtin_amdgcn_global_load_lds((AS1 void*)(uintptr_t)g,
                                     (AS3 void*)(uintptr_t)l, 16, 0, 0);
}

__device__ __forceinline__ u16 f2bf(float f) {
    unsigned u = __float_as_uint(f);
    return (u16)((u + 0x7FFFu + ((u >> 16) & 1u)) >> 16);  // RNE
}

// packed [NF, NX/2] (one byte per int32, two nibbles) -> W bf16 [NF, NX] row-major.
__global__ void dequant_kernel(const int* __restrict__ packed,
                               const float* __restrict__ scales,
                               const int* __restrict__ zeros,
                               uint32_t* __restrict__ W2) {
    int tid = blockIdx.x * blockDim.x + threadIdx.x;   // [0, NF*NX/2)
    int f = tid >> 10;          // NX/2 = 1024 per row
    int i = tid & 1023;
    int g = f * NGROUPS + (i >> 5);
    int p = packed[tid];
    float s = scales[g];
    float z = (float)zeros[g];
    float w0 = ((float)(p & 15) - z) * s;
    float w1 = ((float)((p >> 4) & 15) - z) * s;
    W2[tid] = (uint32_t)f2bf(w0) | ((uint32_t)f2bf(w1) << 16);
}

// ===========================================================================
// 256x256 tile, 8 waves (2Mx4N, wave tile 128x64), BK=64,
// mfma_f32_16x16x32_bf16, ONE block/CU (LDS dbuf 2 x 64 KiB) -- R10's gemm
// (best total, conflicts 0) with the cvt KERNEL FUSED into A staging:
//   A(T+1): 4 global_load_dwordx4 of fp32 x (2+2 batches, 16 VGPR liveness),
//           RNE __bf16 cvt in-reg, ds_write_b128 to the SWIZZLED phys unit.
//           Content bit-identical to R10's glds layout; reads unchanged.
//   B(T+1): R10's glds path verbatim (4 glds, inverse-swizzled source).
// Removes the 13-15us cvt kernel + 64MB Xb HBM round-trip; LDS write bytes
// unchanged (glds wrote LDS too); +~32 VALU/thread/tile on an idle pipe.
//
// Ledgers (per tile, more=staging active):
//  vmem order: [x c0,c1 (4)] [B glds (4)] ... mid: VMC4 drains x-batch1;
//              issue [x c2,c3 (4)]; end: VMCNT0 drains B+x-batch2.
//  lgkm order: [kk0 reads 12][a1 8] LGKM8 | [b1 4] | [w0,w1] LGKM2 |
//              kk1 MFMA | [w2,w3] LGKM0 pre-BAR.
//  WAR on so: its readers (T-1) lgkm-drained pre-BAR(T).  RAW: each wave
//  drains own writes (LGKM0) + B-glds (VMCNT0) before BAR(T+1).
// Tail T=NT-1: no staging; LGKM0 replaces LGKM2 (else b1 not drained).
//
// LDS buffer (64 KiB): A at +0, B at +32768; line = 128B = row's 64 k bf16;
// content(line, phys u) = k-unit u ^ (line&7)  (zero-conflict family,
// measured 0 in R1/R6/R7/R8/R10).  A write: thread t -> line t>>3 (+64c),
// phys = (t&7)^((t>>3)&7), source k-unit = t&7 (straight).  B write: glds
// linear unit t, source k-unit inverse-swizzled.  Reads (16-lane period):
// line = base + i*16 + l15, phys = (kk*4+quad)^(l15&7).
// ===========================================================================

#define BAR    __builtin_amdgcn_s_barrier()
#define LGKM8  asm volatile("s_waitcnt lgkmcnt(8)" ::: "memory")
#define LGKM2  asm volatile("s_waitcnt lgkmcnt(2)" ::: "memory")
#define LGKM0  asm volatile("s_waitcnt lgkmcnt(0)" ::: "memory")
#define VMC4   asm volatile("s_waitcnt vmcnt(4)" ::: "memory")
#define VMCNT0 asm volatile("s_waitcnt vmcnt(0)" ::: "memory")
#define FENCE  __builtin_amdgcn_sched_barrier(0)

#define LD8(off) (*(const bf16x8*)(smem + (off)))

#define MFMA(d, va, vb) d = __builtin_amdgcn_mfma_f32_16x16x32_bf16(va, vb, d, 0, 0, 0)

#define STAGEB(BUF, KOFF) do { \
    glds16(srcB + (KOFF),          smem + (BUF) + 32768 + t16); \
    glds16(srcB + 262144 + (KOFF), smem + (BUF) + 40960 + t16); \
    glds16(srcB + 524288 + (KOFF), smem + (BUF) + 49152 + t16); \
    glds16(srcB + 786432 + (KOFF), smem + (BUF) + 57344 + t16); \
} while (0)

// cvt 8 fp32 -> bf16x8 (RNE) and ds_write_b128 to chunk c of dstA
#define CW(c_, v0_, v1_) do { \
    bf16x8 w_; \
    w_[0] = (__bf16)v0_.x; w_[1] = (__bf16)v0_.y; \
    w_[2] = (__bf16)v0_.z; w_[3] = (__bf16)v0_.w; \
    w_[4] = (__bf16)v1_.x; w_[5] = (__bf16)v1_.y; \
    w_[6] = (__bf16)v1_.z; w_[7] = (__bf16)v1_.w; \
    *(bf16x8*)(dstA + (c_) * 8192) = w_; \
} while (0)

__global__ __launch_bounds__(512, 2)
void gemm_kernel(const float* __restrict__ X, const u16* __restrict__ B,
                 const float* __restrict__ bias, float* __restrict__ C) {
    __shared__ __align__(16) char smem[131072];   // 2 x 64 KiB dbuf

    const int t = threadIdx.x;

    // T1: striped XCD swizzle (R10 verbatim). Grid 1024 = 32 by x 32 bx.
    const int bid = blockIdx.x;
    const int xcd = bid & 7;
    const int local = bid >> 3;          // 0..127
    const int super = local >> 6;        // 0..1
    const int r = local & 63;
    const int by = xcd * 4 + super * 2 + (r & 1);   // 0..31
    const int bx = r >> 1;                          // 0..31
    const int rowA0 = by * 256;
    const int rowB0 = bx * 256;

    // ---- B staging (R10 verbatim: inverse-swizzled source, linear glds) ----
    const int t16 = t * 16;
    const int ulog = (t & 7) ^ ((t >> 3) & 7);
    const int koffS = (ulog >> 2) * 64 + (ulog & 3) * 16;
    const char* srcB = (const char*)B + (size_t)(rowB0 + (t >> 3)) * 4096 + koffS;

    // ---- A x-staging: straight source unit u = t&7, swizzled dest phys=ulog ----
    const int u = t & 7;
    const char* srcX = (const char*)X + (size_t)(rowA0 + (t >> 3)) * 8192
                       + (u >> 2) * 128 + (u & 3) * 32;
    const int aW = (t >> 3) * 128 + ulog * 16;   // + buf + c*8192

    // ---- fragment read addressing (16-lane-period zero-conflict form) ----
    const int lane = t & 63;
    const int wv = t >> 6;
    const int wm = wv >> 2;            // 0..1 (M half, 128 rows)
    const int wn = wv & 3;             // 0..3 (N quarter, 64 cols)
    const int l15 = lane & 15;
    const int quad = lane >> 4;
    const int l7 = l15 & 7;
    const int sx0 = (quad ^ l7) << 4;        // kk=0 unit
    const int sx1 = ((4 + quad) ^ l7) << 4;  // kk=1 unit
    const int aOff = (wm * 128 + l15) * 128;           // + i*2048
    const int bOff = 32768 + (wn * 64 + l15) * 128;    // + j*2048

    f32x4 acc[8][4];
#pragma unroll
    for (int i = 0; i < 8; ++i)
#pragma unroll
        for (int j = 0; j < 4; ++j) acc[i][j] = {0.f, 0.f, 0.f, 0.f};

    bf16x8 a0[8], a1[8], b0[4], b1[4];
    float4 xv0, xv1, xv2, xv3;

    // ---- prologue: stage tile0 -> buf0 ----
    {
        char* dstA = smem + aW;
        xv0 = *(const float4*)(srcX);
        xv1 = *(const float4*)(srcX + 16);
        xv2 = *(const float4*)(srcX + 524288);
        xv3 = *(const float4*)(srcX + 524288 + 16);
        FENCE;
        STAGEB(0, 0);
        FENCE; VMC4; FENCE;            // x batch1 drained; B glds in flight
        CW(0, xv0, xv1); CW(1, xv2, xv3);
        xv0 = *(const float4*)(srcX + 1048576);
        xv1 = *(const float4*)(srcX + 1048576 + 16);
        xv2 = *(const float4*)(srcX + 1572864);
        xv3 = *(const float4*)(srcX + 1572864 + 16);
        FENCE; VMCNT0; FENCE;          // B glds + x batch2 drained
        CW(2, xv0, xv1); CW(3, xv2, xv3);
        LGKM0;                         // own A writes drained; BAR publishes
    }

    int kN = 256;   // fp32 byte K-offset of tile T+1 (bf16 offset = kN>>1)

#pragma unroll 1
    for (int T = 0; T < NT; ++T) {
        const int bo = (T & 1) << 16;   // active buffer
        const int so = bo ^ 65536;      // inactive (receives T+1)
        const bool more = (T + 1 < NT);
        char* dstA = smem + so + aW;

        FENCE; BAR; FENCE;
        if (more) {
            // x batch1 (chunks 0,1) then B glds: vmem order [x4][B4]
            xv0 = *(const float4*)(srcX + kN);
            xv1 = *(const float4*)(srcX + kN + 16);
            xv2 = *(const float4*)(srcX + 524288 + kN);
            xv3 = *(const float4*)(srcX + 524288 + kN + 16);
            FENCE;
            STAGEB(so, kN >> 1);
            FENCE;
        }
        // kk0 reads (12 DS)
#pragma unroll
        for (int i = 0; i < 8; ++i) a0[i] = LD8(bo + aOff + i * 2048 + sx0);
#pragma unroll
        for (int j = 0; j < 4; ++j) b0[j] = LD8(bo + bOff + j * 2048 + sx0);
        FENCE;
        // kk1 A reads (8 DS)
#pragma unroll
        for (int i = 0; i < 8; ++i) a1[i] = LD8(bo + aOff + i * 2048 + sx1);
        FENCE; LGKM8; FENCE;            // a0,b0 ready (oldest 12 of 20)
        __builtin_amdgcn_s_setprio(1);
#pragma unroll
        for (int j = 0; j < 2; ++j)
#pragma unroll
            for (int i = 0; i < 8; ++i) MFMA(acc[i][j], a0[i], b0[j]);
        __builtin_amdgcn_s_setprio(0);
        FENCE;
        // kk1 B reads (4 DS)
#pragma unroll
        for (int j = 0; j < 4; ++j) b1[j] = LD8(bo + bOff + j * 2048 + sx1);
        FENCE;
        __builtin_amdgcn_s_setprio(1);
#pragma unroll
        for (int j = 2; j < 4; ++j)
#pragma unroll
            for (int i = 0; i < 8; ++i) MFMA(acc[i][j], a0[i], b0[j]);
        __builtin_amdgcn_s_setprio(0);
        FENCE;
        if (more) {
            VMC4; FENCE;                // x batch1 landed (B glds stay in flight)
            CW(0, xv0, xv1); CW(1, xv2, xv3);   // lgkm: +2 writes
            // x batch2 (chunks 2,3): drained after kk1 MFMA
            xv0 = *(const float4*)(srcX + 1048576 + kN);
            xv1 = *(const float4*)(srcX + 1048576 + kN + 16);
            xv2 = *(const float4*)(srcX + 1572864 + kN);
            xv3 = *(const float4*)(srcX + 1572864 + kN + 16);
            FENCE; LGKM2; FENCE;        // a1,b1 ready; 2 writes outstanding
        } else {
            LGKM0; FENCE;               // tail: drain a1,b1 fully
        }
        __builtin_amdgcn_s_setprio(1);
#pragma unroll
        for (int j = 0; j < 4; ++j)
#pragma unroll
            for (int i = 0; i < 8; ++i) MFMA(acc[i][j], a1[i], b1[j]);
        __builtin_amdgcn_s_setprio(0);
        FENCE;
        if (more) {
            VMCNT0; FENCE;              // B glds + x batch2 landed
            CW(2, xv0, xv1); CW(3, xv2, xv3);
            LGKM0; FENCE;               // all own writes drained pre-BAR
            kN += 256;
        }
    }

    // ---- epilogue: C/D col = l15, row = quad*4 + e (m89/m91) ----
    const int col0 = rowB0 + wn * 64 + l15;
    const int row0 = rowA0 + wm * 128 + quad * 4;
    float bj[4];
#pragma unroll
    for (int j = 0; j < 4; ++j) bj[j] = bias[col0 + j * 16];
#pragma unroll
    for (int i = 0; i < 8; ++i) {
#pragma unroll
        for (int e = 0; e < 4; ++e) {
            float* crow = C + (size_t)(row0 + i * 16 + e) * NF;
#pragma unroll
            for (int j = 0; j < 4; ++j)
                __builtin_nontemporal_store(acc[i][j][e] + bj[j], crow + col0 + j * 16);
        }
    }
}

extern "C" void kernel_launch(void* const* d_in, const int* in_sizes, int n_in,
                              void* d_out, int out_size, void* d_ws, size_t ws_size,
                              hipStream_t stream) {
    const float* x      = (const float*)d_in[0];   // [4,2048,2048] fp32
    const int* packed   = (const int*)d_in[1];     // [8192,1024]
    const float* scales = (const float*)d_in[2];   // [8192,32]
    const int* zeros    = (const int*)d_in[3];     // [8192,32]
    const float* bias   = (const float*)d_in[4];   // [8192]
    float* out = (float*)d_out;                    // [8192, 8192] fp32

    // workspace: W bf16 (32 MiB) only -- x is read directly by the gemm
    u16* Wq = (u16*)d_ws;

    dequant_kernel<<<(NF * (NX / 2)) / 256, 256, 0, stream>>>(packed, scales, zeros, (uint32_t*)Wq);

    gemm_kernel<<<dim3((MROWS / 256) * (NF / 256)), 512, 0, stream>>>(x, Wq, bias, out);
}